// Round 3
// baseline (642.676 us; speedup 1.0000x reference)
//
#include <hip/hip_runtime.h>
#include <math.h>

// GNN gated-graph layer: B=64, N=27, C=512, L=2. fp32 in/out, bf16 MFMA GEMMs.
#define NN 27
#define NE 729
#define CC 512
#define BB 64
#define EPSV 1e-5f
#define XROWS (BB*NN)    // 1728
#define EROWS (BB*NE)    // 46656
#define WSZ   (CC*CC)    // 262144 = 2^18

typedef short s16x8 __attribute__((ext_vector_type(8)));   // 8 bf16
typedef float f32x4 __attribute__((ext_vector_type(4)));
typedef unsigned short bfu_t;
typedef const __attribute__((address_space(1))) void gv_t;
typedef __attribute__((address_space(3))) void lv_t;

static __device__ __forceinline__ bfu_t f2bu(float f) {
    __bf16 h = (__bf16)f;                       // RNE
    return __builtin_bit_cast(unsigned short, h);
}

// ---------------- zero the stats scratch (1536 floats) ----------------------
__global__ __launch_bounds__(256)
void zero_stats(float* __restrict__ p)
{
    p[blockIdx.x * 256 + threadIdx.x] = 0.f;
}

// ---------------- one-shot fp32 -> bf16 conversion of everything ------------
// segments: [10 x WSZ weights: l0{a,b,v,u}, l1{a,b,v,u}, We_l0, We_l1] [x0] [e0]
__global__ __launch_bounds__(256)
void convert_all(const float* __restrict__ Wa, const float* __restrict__ Wb,
                 const float* __restrict__ Wv, const float* __restrict__ Wu,
                 const float* __restrict__ We, const float* __restrict__ x0,
                 const float* __restrict__ e0,
                 bfu_t* __restrict__ WnB, bfu_t* __restrict__ WeB,
                 bfu_t* __restrict__ xbf, bfu_t* __restrict__ ebf)
{
    const long i = (long)(blockIdx.x * 256 + threadIdx.x) * 8;
    const long WTOT = 10L * WSZ;
    const long XTOT = WTOT + (long)XROWS * CC;
    const float* src;
    bfu_t* dst;
    if (i < WTOT) {
        int  c   = (int)(i >> 18);
        long off = i & (WSZ - 1);
        if (c < 8) {
            int l = c >> 2, t = c & 3;
            const float* b = (t == 0) ? Wa : (t == 1) ? Wb : (t == 2) ? Wv : Wu;
            src = b + (long)l * WSZ + off;
            dst = WnB + (long)c * WSZ + off;
        } else {
            src = We + (long)(c - 8) * WSZ + off;
            dst = WeB + (long)(c - 8) * WSZ + off;
        }
    } else if (i < XTOT) {
        long off = i - WTOT;
        src = x0 + off;  dst = xbf + off;
    } else {
        long off = i - XTOT;
        src = e0 + off;  dst = ebf + off;
    }
    float4 a = *(const float4*)src;
    float4 b = *(const float4*)(src + 4);
    s16x8 v;
    v[0] = (short)f2bu(a.x); v[1] = (short)f2bu(a.y);
    v[2] = (short)f2bu(a.z); v[3] = (short)f2bu(a.w);
    v[4] = (short)f2bu(b.x); v[5] = (short)f2bu(b.y);
    v[6] = (short)f2bu(b.z); v[7] = (short)f2bu(b.w);
    *(s16x8*)dst = v;
}

// ---------------- bf16 MFMA GEMM: out = A @ W^T -----------------------------
// mode 0: out[row*ldo + bn + col] = acc                          (node -> xW)
// mode 1: out[row*512 + col] = acc + Ax[i] + Bx[j]; atomic BN stats per e
__global__ __launch_bounds__(256)
void gemm_mfma(const bfu_t* __restrict__ A, const bfu_t* __restrict__ W,
               float* __restrict__ out, int M, int ldo,
               const float* __restrict__ xW, int mode,
               float* __restrict__ esum, float* __restrict__ esumsq)
{
    __shared__ bfu_t As[128 * 32];
    __shared__ bfu_t Bs[128 * 32];

    const int t    = threadIdx.x;
    const int lane = t & 63;
    const int w    = t >> 6;
    const int bm   = blockIdx.x * 128;
    const int bn   = blockIdx.y * 128;
    const int wr   = (w >> 1) * 64;
    const int wc   = (w & 1) * 64;

    f32x4 acc[4][4];
    #pragma unroll
    for (int i = 0; i < 4; ++i)
        #pragma unroll
        for (int j = 0; j < 4; ++j) acc[i][j] = (f32x4){0.f, 0.f, 0.f, 0.f};

    const int r0 = w * 32 + (lane >> 2);
    const int r1 = r0 + 16;
    const int kc = (lane & 3) * 8;
    int ga0 = bm + r0; if (ga0 > M - 1) ga0 = M - 1;
    int ga1 = bm + r1; if (ga1 > M - 1) ga1 = M - 1;
    const bfu_t* a0 = A + (size_t)ga0 * CC + kc;
    const bfu_t* a1 = A + (size_t)ga1 * CC + kc;
    const bfu_t* w0 = W + (size_t)(bn + r0) * CC + kc;
    const bfu_t* w1 = W + (size_t)(bn + r1) * CC + kc;
    bfu_t* lA0 = As + (w * 2 + 0) * 512;
    bfu_t* lA1 = As + (w * 2 + 1) * 512;
    bfu_t* lB0 = Bs + (w * 2 + 0) * 512;
    bfu_t* lB1 = Bs + (w * 2 + 1) * 512;

    const int fra = wr + (lane & 15);
    const int frb = wc + (lane & 15);
    const int fk  = (lane >> 4) * 8;

    for (int kt = 0; kt < CC; kt += 32) {
        if (kt) __syncthreads();
        __builtin_amdgcn_global_load_lds((gv_t*)(a0 + kt), (lv_t*)lA0, 16, 0, 0);
        __builtin_amdgcn_global_load_lds((gv_t*)(a1 + kt), (lv_t*)lA1, 16, 0, 0);
        __builtin_amdgcn_global_load_lds((gv_t*)(w0 + kt), (lv_t*)lB0, 16, 0, 0);
        __builtin_amdgcn_global_load_lds((gv_t*)(w1 + kt), (lv_t*)lB1, 16, 0, 0);
        __syncthreads();

        s16x8 af[4], bfg[4];
        #pragma unroll
        for (int i = 0; i < 4; ++i)
            af[i] = *(const s16x8*)&As[(fra + i * 16) * 32 + fk];
        #pragma unroll
        for (int i = 0; i < 4; ++i)
            bfg[i] = *(const s16x8*)&Bs[(frb + i * 16) * 32 + fk];
        #pragma unroll
        for (int i = 0; i < 4; ++i)
            #pragma unroll
            for (int j = 0; j < 4; ++j)
                acc[i][j] = __builtin_amdgcn_mfma_f32_16x16x32_bf16(af[i], bfg[j], acc[i][j], 0, 0, 0);
    }

    const int crb = wr + ((lane >> 4) << 2);
    const int ccb = wc + (lane & 15);
    if (mode == 0) {
        #pragma unroll
        for (int mi = 0; mi < 4; ++mi) {
            #pragma unroll
            for (int q = 0; q < 4; ++q) {
                int row = bm + crb + mi * 16 + q;
                if (row >= M) continue;
                float* o = out + (size_t)row * ldo + bn + ccb;
                #pragma unroll
                for (int ni = 0; ni < 4; ++ni) o[ni * 16] = acc[mi][ni][q];
            }
        }
    } else {
        #pragma unroll
        for (int mi = 0; mi < 4; ++mi) {
            #pragma unroll
            for (int q = 0; q < 4; ++q) {
                int row = bm + crb + mi * 16 + q;
                if (row >= M) continue;    // uniform across each 16-lane group
                int b  = row / NE;
                int e  = row - b * NE;
                int i2 = e / NN;
                int j2 = e - i2 * NN;
                const float* axp = xW + (size_t)(b * NN + i2) * 2048 + bn + ccb;
                const float* bxp = xW + (size_t)(b * NN + j2) * 2048 + 512 + bn + ccb;
                float* o = out + (size_t)row * CC + bn + ccb;
                float s = 0.f, sq = 0.f;
                #pragma unroll
                for (int ni = 0; ni < 4; ++ni) {
                    float v = acc[mi][ni][q] + axp[ni * 16] + bxp[ni * 16];
                    o[ni * 16] = v;
                    s += v; sq += v * v;
                }
                // reduce over the 16 lanes holding this row's 64 cols
                #pragma unroll
                for (int off = 1; off < 16; off <<= 1) {
                    s  += __shfl_xor(s, off);
                    sq += __shfl_xor(sq, off);
                }
                if ((lane & 15) == 0) {
                    atomicAdd(&esum[e], s);
                    atomicAdd(&esumsq[e], sq);
                }
            }
        }
    }
}

// ---------------- fused: BN(m)+relu+residual -> eout/ebf -> softmax -> agg --
// block = (b,i), 256 threads, 2 channels/thread.
__global__ __launch_bounds__(256)
void agg_edge(const float* __restrict__ m, const float* __restrict__ ein,
              float* __restrict__ eout, bfu_t* __restrict__ ebf,
              const float* __restrict__ xW, float* __restrict__ xpre,
              const float* __restrict__ esum, const float* __restrict__ esumsq,
              const float* __restrict__ bnew, const float* __restrict__ bneb,
              float* __restrict__ vsum, float* __restrict__ vsumsq)
{
    const int bi = blockIdx.x;
    const int b  = bi / NN;
    const int i  = bi - b * NN;
    const int c  = threadIdx.x * 2;

    __shared__ float kae[NN], kbe[NN];
    if (threadIdx.x < NN) {
        int e = i * NN + threadIdx.x;
        const float inv = 1.f / (float)(BB * CC);
        float mean = esum[e] * inv;
        float var  = esumsq[e] * inv - mean * mean;
        float r    = rsqrtf(var + EPSV);
        float a    = r * bnew[e];
        kae[threadIdx.x] = a;
        kbe[threadIdx.x] = bneb[e] - mean * a;
    }
    __syncthreads();

    const size_t ebase = ((size_t)b * NE + (size_t)i * NN) * CC + c;
    float2 ex[NN];
    float2 den = {0.f, 0.f};
    #pragma unroll
    for (int j = 0; j < NN; ++j) {
        size_t idx = ebase + (size_t)j * CC;
        float2 mv = *(const float2*)(m + idx);
        float2 ev = *(const float2*)(ein + idx);
        float a = kae[j], bb = kbe[j];
        float2 o;
        o.x = ev.x + fmaxf(fmaf(mv.x, a, bb), 0.f);
        o.y = ev.y + fmaxf(fmaf(mv.y, a, bb), 0.f);
        *(float2*)(eout + idx) = o;
        ushort2 h; h.x = f2bu(o.x); h.y = f2bu(o.y);
        *(ushort2*)(ebf + idx) = h;
        float sx = 1.f / (1.f + __expf(-o.x));
        float sy = 1.f / (1.f + __expf(-o.y));
        float gx = __expf(sx), gy = __expf(sy);
        ex[j].x = gx; ex[j].y = gy;
        den.x += gx; den.y += gy;
    }

    float2 accv = {0.f, 0.f};
    const float* vb = xW + (size_t)(b * NN) * 2048 + 1024 + c;
    #pragma unroll
    for (int j = 0; j < NN; ++j) {
        float2 v = *(const float2*)(vb + (size_t)j * 2048);
        accv.x = fmaf(ex[j].x, v.x, accv.x);
        accv.y = fmaf(ex[j].y, v.y, accv.y);
    }
    float2 u = *(const float2*)(xW + (size_t)bi * 2048 + 1536 + c);
    float2 xp;
    xp.x = u.x + accv.x / (den.x * (float)NN);
    xp.y = u.y + accv.y / (den.y * (float)NN);
    *(float2*)(xpre + (size_t)bi * CC + c) = xp;

    // node-BN partial stats for channel i over this (b,i) row
    float s  = xp.x + xp.y;
    float sq = xp.x * xp.x + xp.y * xp.y;
    #pragma unroll
    for (int off = 32; off; off >>= 1) {
        s  += __shfl_down(s, off);
        sq += __shfl_down(sq, off);
    }
    __shared__ float rs[4], rq[4];
    const int wid = threadIdx.x >> 6, lane = threadIdx.x & 63;
    if (lane == 0) { rs[wid] = s; rq[wid] = sq; }
    __syncthreads();
    if (threadIdx.x == 0) {
        atomicAdd(&vsum[i],   rs[0] + rs[1] + rs[2] + rs[3]);
        atomicAdd(&vsumsq[i], rq[0] + rq[1] + rq[2] + rq[3]);
    }
}

// ---------------- node update: xout = xpre + relu(bn(xpre)), + bf16 copy ----
__global__ __launch_bounds__(256)
void x_update(const float* __restrict__ xpre, float* __restrict__ xout,
              bfu_t* __restrict__ xbf,
              const float* __restrict__ vsum, const float* __restrict__ vsumsq,
              const float* __restrict__ bnvw, const float* __restrict__ bnvb)
{
    const int idx = blockIdx.x * 256 + threadIdx.x;   // float4 idx, 221184 total
    const int i = (idx >> 7) % NN;
    const float inv = 1.f / (float)(BB * CC);
    float mean = vsum[i] * inv;
    float var  = vsumsq[i] * inv - mean * mean;
    float r    = rsqrtf(var + EPSV);
    float a    = r * bnvw[i];
    float b    = bnvb[i] - mean * a;
    float4 v = ((const float4*)xpre)[idx];
    float4 o;
    o.x = v.x + fmaxf(fmaf(v.x, a, b), 0.f);
    o.y = v.y + fmaxf(fmaf(v.y, a, b), 0.f);
    o.z = v.z + fmaxf(fmaf(v.z, a, b), 0.f);
    o.w = v.w + fmaxf(fmaf(v.w, a, b), 0.f);
    ((float4*)xout)[idx] = o;
    ushort4 h;
    h.x = f2bu(o.x); h.y = f2bu(o.y); h.z = f2bu(o.z); h.w = f2bu(o.w);
    ((ushort4*)xbf)[idx] = h;
}

// ---------------------------------------------------------------------------
extern "C" void kernel_launch(void* const* d_in, const int* in_sizes, int n_in,
                              void* d_out, int out_size, void* d_ws, size_t ws_size,
                              hipStream_t stream)
{
    const float* x0   = (const float*)d_in[0];
    const float* e0   = (const float*)d_in[1];
    const float* Wu   = (const float*)d_in[2];
    const float* Wv   = (const float*)d_in[3];
    const float* Wa   = (const float*)d_in[4];
    const float* Wb   = (const float*)d_in[5];
    const float* We   = (const float*)d_in[6];
    const float* bnvw = (const float*)d_in[7];
    const float* bnvb = (const float*)d_in[8];
    const float* bnew = (const float*)d_in[9];
    const float* bneb = (const float*)d_in[10];

    const size_t XSZ = (size_t)XROWS * CC;     // 884736
    const size_t ESZ = (size_t)EROWS * CC;     // 23887872

    float* xout = (float*)d_out;
    float* eout = xout + XSZ;

    // fp32 workspace
    float* ws    = (float*)d_ws;
    float* xW    = ws;                          // [1728][2048] A|B|V|U cols
    float* m     = xW + (size_t)XROWS * 2048;
    float* xpre  = m + ESZ;
    float* stats = xpre + XSZ;                  // 1536 floats
    float* esum  = stats;
    float* esumsq = stats + NE;
    float* vsum   = stats + 2 * NE;
    float* vsumsq = stats + 2 * NE + NN;
    // bf16 workspace
    bfu_t* bws = (bfu_t*)(stats + 1536);
    bfu_t* ebf = bws;                                  // [46656][512]
    bfu_t* xbf = ebf + ESZ;                            // [1728][512]
    bfu_t* WnB = xbf + XSZ;                            // [L][2048][512]
    bfu_t* WeB = WnB + (size_t)2 * 2048 * CC;          // [L][512][512]

    // one-shot conversion: weights (both layers) + layer-0 activations
    const long CTOT = 10L * WSZ + (long)XSZ + (long)ESZ;   // 27394048
    convert_all<<<(int)(CTOT / 8 / 256), 256, 0, stream>>>(
        Wa, Wb, Wv, Wu, We, x0, e0, WnB, WeB, xbf, ebf);

    const dim3 gN(14, 16);    // node: M=1728, N=2048
    const dim3 gE(365, 4);    // edge: M=46656, N=512

    for (int l = 0; l < 2; ++l) {
        const float* ei = l ? (const float*)eout : e0;

        zero_stats<<<6, 256, 0, stream>>>(stats);

        gemm_mfma<<<gN, 256, 0, stream>>>(xbf, WnB + (size_t)l * 4 * WSZ,
                                          xW, XROWS, 2048, nullptr, 0,
                                          nullptr, nullptr);
        gemm_mfma<<<gE, 256, 0, stream>>>(ebf, WeB + (size_t)l * WSZ,
                                          m, EROWS, CC, xW, 1, esum, esumsq);

        agg_edge<<<XROWS, 256, 0, stream>>>(m, ei, eout, ebf, xW, xpre,
                                            esum, esumsq,
                                            bnew + (size_t)l * NE,
                                            bneb + (size_t)l * NE,
                                            vsum, vsumsq);

        x_update<<<(int)(XSZ / 4 / 256), 256, 0, stream>>>(
            xpre, xout, xbf, vsum, vsumsq,
            bnvw + (size_t)l * NN, bnvb + (size_t)l * NN);
    }
}

// Round 4
// 554.908 us; speedup vs baseline: 1.1582x; 1.1582x over previous
//
#include <hip/hip_runtime.h>
#include <math.h>

// GNN gated-graph layer: B=64, N=27, C=512, L=2. fp32 in/out, bf16 MFMA GEMMs.
#define NN 27
#define NE 729
#define CC 512
#define BB 64
#define EPSV 1e-5f
#define XROWS (BB*NN)    // 1728
#define EROWS (BB*NE)    // 46656
#define WSZ   (CC*CC)    // 262144 = 2^18

typedef short s16x8 __attribute__((ext_vector_type(8)));   // 8 bf16
typedef float f32x4 __attribute__((ext_vector_type(4)));
typedef unsigned short bfu_t;
typedef const __attribute__((address_space(1))) void gv_t;
typedef __attribute__((address_space(3))) void lv_t;

static __device__ __forceinline__ bfu_t f2bu(float f) {
    __bf16 h = (__bf16)f;                       // RNE
    return __builtin_bit_cast(unsigned short, h);
}

// bijective XCD-aware swizzle (m204): consecutive hardware slots round-robin
// XCDs; remap so each XCD owns a contiguous chunk of tile ids.
static __device__ __forceinline__ int xcd_swz(int id, int nwg) {
    int q = nwg >> 3, r = nwg & 7;
    int xcd = id & 7, off = id >> 3;
    return (xcd < r ? xcd * (q + 1) : r * (q + 1) + (xcd - r) * q) + off;
}

// ---------------- one-shot fp32 -> bf16 conversion of everything ------------
__global__ __launch_bounds__(256)
void convert_all(const float* __restrict__ Wa, const float* __restrict__ Wb,
                 const float* __restrict__ Wv, const float* __restrict__ Wu,
                 const float* __restrict__ We, const float* __restrict__ x0,
                 const float* __restrict__ e0,
                 bfu_t* __restrict__ WnB, bfu_t* __restrict__ WeB,
                 bfu_t* __restrict__ xbf, bfu_t* __restrict__ ebf)
{
    const long i = (long)(blockIdx.x * 256 + threadIdx.x) * 8;
    const long WTOT = 10L * WSZ;
    const long XTOT = WTOT + (long)XROWS * CC;
    const float* src;
    bfu_t* dst;
    if (i < WTOT) {
        int  c   = (int)(i >> 18);
        long off = i & (WSZ - 1);
        if (c < 8) {
            int l = c >> 2, t = c & 3;
            const float* b = (t == 0) ? Wa : (t == 1) ? Wb : (t == 2) ? Wv : Wu;
            src = b + (long)l * WSZ + off;
            dst = WnB + (long)c * WSZ + off;
        } else {
            src = We + (long)(c - 8) * WSZ + off;
            dst = WeB + (long)(c - 8) * WSZ + off;
        }
    } else if (i < XTOT) {
        long off = i - WTOT;
        src = x0 + off;  dst = xbf + off;
    } else {
        long off = i - XTOT;
        src = e0 + off;  dst = ebf + off;
    }
    float4 a = *(const float4*)src;
    float4 b = *(const float4*)(src + 4);
    s16x8 v;
    v[0] = (short)f2bu(a.x); v[1] = (short)f2bu(a.y);
    v[2] = (short)f2bu(a.z); v[3] = (short)f2bu(a.w);
    v[4] = (short)f2bu(b.x); v[5] = (short)f2bu(b.y);
    v[6] = (short)f2bu(b.z); v[7] = (short)f2bu(b.w);
    *(s16x8*)dst = v;
}

// ---------------- bf16 MFMA GEMM: out = A @ W^T -----------------------------
// 1D grid (XCD-swizzled), gy = column-block count.
// mode 0: out[row*ldo + bn + col] = acc                          (node -> xW)
// mode 1: out[row*512 + col] = acc + Ax[i] + Bx[j];
//         per-(colchunk,row) BN partial {sum,sumsq} -> pstat (no atomics)
__global__ __launch_bounds__(256)
void gemm_mfma(const bfu_t* __restrict__ A, const bfu_t* __restrict__ W,
               float* __restrict__ out, int M, int ldo, int gy,
               const float* __restrict__ xW, int mode,
               float2* __restrict__ pstat)
{
    __shared__ bfu_t As[128 * 32];
    __shared__ bfu_t Bs[128 * 32];

    const int nwg  = gridDim.x;
    const int wgid = xcd_swz(blockIdx.x, nwg);
    const int bm   = (wgid / gy) * 128;
    const int by   = wgid % gy;
    const int bn   = by * 128;

    const int t    = threadIdx.x;
    const int lane = t & 63;
    const int w    = t >> 6;
    const int wr   = (w >> 1) * 64;
    const int wc   = (w & 1) * 64;

    f32x4 acc[4][4];
    #pragma unroll
    for (int i = 0; i < 4; ++i)
        #pragma unroll
        for (int j = 0; j < 4; ++j) acc[i][j] = (f32x4){0.f, 0.f, 0.f, 0.f};

    const int r0 = w * 32 + (lane >> 2);
    const int r1 = r0 + 16;
    const int kc = (lane & 3) * 8;
    int ga0 = bm + r0; if (ga0 > M - 1) ga0 = M - 1;
    int ga1 = bm + r1; if (ga1 > M - 1) ga1 = M - 1;
    const bfu_t* a0 = A + (size_t)ga0 * CC + kc;
    const bfu_t* a1 = A + (size_t)ga1 * CC + kc;
    const bfu_t* w0 = W + (size_t)(bn + r0) * CC + kc;
    const bfu_t* w1 = W + (size_t)(bn + r1) * CC + kc;
    bfu_t* lA0 = As + (w * 2 + 0) * 512;
    bfu_t* lA1 = As + (w * 2 + 1) * 512;
    bfu_t* lB0 = Bs + (w * 2 + 0) * 512;
    bfu_t* lB1 = Bs + (w * 2 + 1) * 512;

    const int fra = wr + (lane & 15);
    const int frb = wc + (lane & 15);
    const int fk  = (lane >> 4) * 8;

    for (int kt = 0; kt < CC; kt += 32) {
        if (kt) __syncthreads();
        __builtin_amdgcn_global_load_lds((gv_t*)(a0 + kt), (lv_t*)lA0, 16, 0, 0);
        __builtin_amdgcn_global_load_lds((gv_t*)(a1 + kt), (lv_t*)lA1, 16, 0, 0);
        __builtin_amdgcn_global_load_lds((gv_t*)(w0 + kt), (lv_t*)lB0, 16, 0, 0);
        __builtin_amdgcn_global_load_lds((gv_t*)(w1 + kt), (lv_t*)lB1, 16, 0, 0);
        __syncthreads();

        s16x8 af[4], bfg[4];
        #pragma unroll
        for (int i = 0; i < 4; ++i)
            af[i] = *(const s16x8*)&As[(fra + i * 16) * 32 + fk];
        #pragma unroll
        for (int i = 0; i < 4; ++i)
            bfg[i] = *(const s16x8*)&Bs[(frb + i * 16) * 32 + fk];
        #pragma unroll
        for (int i = 0; i < 4; ++i)
            #pragma unroll
            for (int j = 0; j < 4; ++j)
                acc[i][j] = __builtin_amdgcn_mfma_f32_16x16x32_bf16(af[i], bfg[j], acc[i][j], 0, 0, 0);
    }

    const int crb = wr + ((lane >> 4) << 2);
    const int ccb = wc + (lane & 15);
    if (mode == 0) {
        #pragma unroll
        for (int mi = 0; mi < 4; ++mi) {
            #pragma unroll
            for (int q = 0; q < 4; ++q) {
                int row = bm + crb + mi * 16 + q;
                if (row >= M) continue;
                float* o = out + (size_t)row * ldo + bn + ccb;
                #pragma unroll
                for (int ni = 0; ni < 4; ++ni) o[ni * 16] = acc[mi][ni][q];
            }
        }
    } else {
        const int chunk = by * 2 + (w & 1);      // 8 col-chunks of 64
        #pragma unroll
        for (int mi = 0; mi < 4; ++mi) {
            #pragma unroll
            for (int q = 0; q < 4; ++q) {
                int row = bm + crb + mi * 16 + q;
                if (row >= M) continue;
                int b  = row / NE;
                int e  = row - b * NE;
                int i2 = e / NN;
                int j2 = e - i2 * NN;
                const float* axp = xW + (size_t)(b * NN + i2) * 2048 + bn + ccb;
                const float* bxp = xW + (size_t)(b * NN + j2) * 2048 + 512 + bn + ccb;
                float* o = out + (size_t)row * CC + bn + ccb;
                float s = 0.f, sq = 0.f;
                #pragma unroll
                for (int ni = 0; ni < 4; ++ni) {
                    float v = acc[mi][ni][q] + axp[ni * 16] + bxp[ni * 16];
                    o[ni * 16] = v;
                    s += v; sq += v * v;
                }
                #pragma unroll
                for (int off = 1; off < 16; off <<= 1) {
                    s  += __shfl_xor(s, off);
                    sq += __shfl_xor(sq, off);
                }
                if ((lane & 15) == 0)
                    pstat[(size_t)chunk * EROWS + row] = make_float2(s, sq);
            }
        }
    }
}

// ---------------- reduce edge BN partials -> kae/kbe; zero node stats -------
__global__ __launch_bounds__(256)
void reduce_estats(const float2* __restrict__ pstat,
                   const float* __restrict__ bnew, const float* __restrict__ bneb,
                   float* __restrict__ kae, float* __restrict__ kbe,
                   float* __restrict__ vstats)
{
    const int e = blockIdx.x;
    const int t = threadIdx.x;
    if (e == 0 && t < 2 * NN) vstats[t] = 0.f;

    float s = 0.f, sq = 0.f;
    #pragma unroll
    for (int k = t; k < 512; k += 256) {
        int chunk = k >> 6, b = k & 63;
        float2 v = pstat[(size_t)chunk * EROWS + (size_t)b * NE + e];
        s += v.x; sq += v.y;
    }
    #pragma unroll
    for (int off = 32; off; off >>= 1) {
        s  += __shfl_down(s, off);
        sq += __shfl_down(sq, off);
    }
    __shared__ float rs[4], rq[4];
    const int wid = t >> 6, lane = t & 63;
    if (lane == 0) { rs[wid] = s; rq[wid] = sq; }
    __syncthreads();
    if (t == 0) {
        s  = rs[0] + rs[1] + rs[2] + rs[3];
        sq = rq[0] + rq[1] + rq[2] + rq[3];
        const float inv = 1.f / (float)(BB * CC);
        float mean = s * inv;
        float var  = sq * inv - mean * mean;
        float r    = rsqrtf(var + EPSV);
        float a    = r * bnew[e];
        kae[e] = a;
        kbe[e] = bneb[e] - mean * a;
    }
}

// ---------------- fused: BN(m)+relu+residual -> eout/ebf -> softmax -> agg --
__global__ __launch_bounds__(256)
void agg_edge(const float* __restrict__ m, const float* __restrict__ ein,
              float* __restrict__ eout, bfu_t* __restrict__ ebf,
              const float* __restrict__ xW, float* __restrict__ xpre,
              const float* __restrict__ kae, const float* __restrict__ kbe,
              float* __restrict__ vsum, float* __restrict__ vsumsq)
{
    const int bi = blockIdx.x;
    const int b  = bi / NN;
    const int i  = bi - b * NN;
    const int c  = threadIdx.x * 2;

    __shared__ float ka_s[NN], kb_s[NN];
    if (threadIdx.x < NN) {
        ka_s[threadIdx.x] = kae[i * NN + threadIdx.x];
        kb_s[threadIdx.x] = kbe[i * NN + threadIdx.x];
    }
    __syncthreads();

    const size_t ebase = ((size_t)b * NE + (size_t)i * NN) * CC + c;
    float2 ex[NN];
    float2 den = {0.f, 0.f};
    #pragma unroll
    for (int j = 0; j < NN; ++j) {
        size_t idx = ebase + (size_t)j * CC;
        float2 mv = *(const float2*)(m + idx);
        float2 ev = *(const float2*)(ein + idx);
        float a = ka_s[j], bb = kb_s[j];
        float2 o;
        o.x = ev.x + fmaxf(fmaf(mv.x, a, bb), 0.f);
        o.y = ev.y + fmaxf(fmaf(mv.y, a, bb), 0.f);
        *(float2*)(eout + idx) = o;
        ushort2 h; h.x = f2bu(o.x); h.y = f2bu(o.y);
        *(ushort2*)(ebf + idx) = h;
        float sx = 1.f / (1.f + __expf(-o.x));
        float sy = 1.f / (1.f + __expf(-o.y));
        float gx = __expf(sx), gy = __expf(sy);
        ex[j].x = gx; ex[j].y = gy;
        den.x += gx; den.y += gy;
    }

    float2 accv = {0.f, 0.f};
    const float* vb = xW + (size_t)(b * NN) * 2048 + 1024 + c;
    #pragma unroll
    for (int j = 0; j < NN; ++j) {
        float2 v = *(const float2*)(vb + (size_t)j * 2048);
        accv.x = fmaf(ex[j].x, v.x, accv.x);
        accv.y = fmaf(ex[j].y, v.y, accv.y);
    }
    float2 u = *(const float2*)(xW + (size_t)bi * 2048 + 1536 + c);
    float2 xp;
    xp.x = u.x + accv.x / (den.x * (float)NN);
    xp.y = u.y + accv.y / (den.y * (float)NN);
    *(float2*)(xpre + (size_t)bi * CC + c) = xp;

    float s  = xp.x + xp.y;
    float sq = xp.x * xp.x + xp.y * xp.y;
    #pragma unroll
    for (int off = 32; off; off >>= 1) {
        s  += __shfl_down(s, off);
        sq += __shfl_down(sq, off);
    }
    __shared__ float rs[4], rq[4];
    const int wid = threadIdx.x >> 6, lane = threadIdx.x & 63;
    if (lane == 0) { rs[wid] = s; rq[wid] = sq; }
    __syncthreads();
    if (threadIdx.x == 0) {
        atomicAdd(&vsum[i],   rs[0] + rs[1] + rs[2] + rs[3]);
        atomicAdd(&vsumsq[i], rq[0] + rq[1] + rq[2] + rq[3]);
    }
}

// ---------------- node update: xout = xpre + relu(bn(xpre)), + bf16 copy ----
__global__ __launch_bounds__(256)
void x_update(const float* __restrict__ xpre, float* __restrict__ xout,
              bfu_t* __restrict__ xbf,
              const float* __restrict__ vsum, const float* __restrict__ vsumsq,
              const float* __restrict__ bnvw, const float* __restrict__ bnvb)
{
    const int idx = blockIdx.x * 256 + threadIdx.x;   // float4 idx
    const int i = (idx >> 7) % NN;
    const float inv = 1.f / (float)(BB * CC);
    float mean = vsum[i] * inv;
    float var  = vsumsq[i] * inv - mean * mean;
    float r    = rsqrtf(var + EPSV);
    float a    = r * bnvw[i];
    float b    = bnvb[i] - mean * a;
    float4 v = ((const float4*)xpre)[idx];
    float4 o;
    o.x = v.x + fmaxf(fmaf(v.x, a, b), 0.f);
    o.y = v.y + fmaxf(fmaf(v.y, a, b), 0.f);
    o.z = v.z + fmaxf(fmaf(v.z, a, b), 0.f);
    o.w = v.w + fmaxf(fmaf(v.w, a, b), 0.f);
    ((float4*)xout)[idx] = o;
    ushort4 h;
    h.x = f2bu(o.x); h.y = f2bu(o.y); h.z = f2bu(o.z); h.w = f2bu(o.w);
    ((ushort4*)xbf)[idx] = h;
}

// ---------------------------------------------------------------------------
extern "C" void kernel_launch(void* const* d_in, const int* in_sizes, int n_in,
                              void* d_out, int out_size, void* d_ws, size_t ws_size,
                              hipStream_t stream)
{
    const float* x0   = (const float*)d_in[0];
    const float* e0   = (const float*)d_in[1];
    const float* Wu   = (const float*)d_in[2];
    const float* Wv   = (const float*)d_in[3];
    const float* Wa   = (const float*)d_in[4];
    const float* Wb   = (const float*)d_in[5];
    const float* We   = (const float*)d_in[6];
    const float* bnvw = (const float*)d_in[7];
    const float* bnvb = (const float*)d_in[8];
    const float* bnew = (const float*)d_in[9];
    const float* bneb = (const float*)d_in[10];

    const size_t XSZ = (size_t)XROWS * CC;     // 884736
    const size_t ESZ = (size_t)EROWS * CC;     // 23887872

    float* xout = (float*)d_out;
    float* eout = xout + XSZ;

    // fp32 workspace
    float* ws    = (float*)d_ws;
    float* xW    = ws;                          // [1728][2048] A|B|V|U cols
    float* m     = xW + (size_t)XROWS * 2048;
    float* xpre  = m + ESZ;
    float* kae   = xpre + XSZ;                  // 729
    float* kbe   = kae + NE;                    // 729
    float* vstats = kbe + NE;                   // 54 (+pad to 64)
    float* vsum   = vstats;
    float* vsumsq = vstats + NN;
    float2* pstat = (float2*)(vstats + 64);     // [8][EROWS] float2
    // bf16 workspace
    bfu_t* bws = (bfu_t*)(pstat + (size_t)8 * EROWS);
    bfu_t* ebf = bws;                                  // [46656][512]
    bfu_t* xbf = ebf + ESZ;                            // [1728][512]
    bfu_t* WnB = xbf + XSZ;                            // [L][2048][512]
    bfu_t* WeB = WnB + (size_t)2 * 2048 * CC;          // [L][512][512]

    const long CTOT = 10L * WSZ + (long)XSZ + (long)ESZ;
    convert_all<<<(int)(CTOT / 8 / 256), 256, 0, stream>>>(
        Wa, Wb, Wv, Wu, We, x0, e0, WnB, WeB, xbf, ebf);

    const int nwgN = 14 * 16;     // node: M=1728 (14 tiles), N=2048 (16 tiles)
    const int nwgE = 365 * 4;     // edge: M=46656 (365), N=512 (4)

    for (int l = 0; l < 2; ++l) {
        const float* ei = l ? (const float*)eout : e0;

        gemm_mfma<<<nwgN, 256, 0, stream>>>(xbf, WnB + (size_t)l * 4 * WSZ,
                                            xW, XROWS, 2048, 16, nullptr, 0, nullptr);
        gemm_mfma<<<nwgE, 256, 0, stream>>>(ebf, WeB + (size_t)l * WSZ,
                                            m, EROWS, CC, 4, xW, 1, pstat);

        reduce_estats<<<NE, 256, 0, stream>>>(pstat,
                                              bnew + (size_t)l * NE,
                                              bneb + (size_t)l * NE,
                                              kae, kbe, vstats);

        agg_edge<<<XROWS, 256, 0, stream>>>(m, ei, eout, ebf, xW, xpre,
                                            kae, kbe, vsum, vsumsq);

        x_update<<<(int)(XSZ / 4 / 256), 256, 0, stream>>>(
            xpre, xout, xbf, vsum, vsumsq,
            bnvw + (size_t)l * NN, bnvb + (size_t)l * NN);
    }
}

// Round 5
// 508.419 us; speedup vs baseline: 1.2641x; 1.0914x over previous
//
#include <hip/hip_runtime.h>
#include <math.h>

// GNN gated-graph layer: B=64, N=27, C=512, L=2. fp32 in/out, bf16 MFMA GEMMs.
#define NN 27
#define NE 729
#define CC 512
#define BB 64
#define EPSV 1e-5f
#define XROWS (BB*NN)    // 1728
#define EROWS (BB*NE)    // 46656
#define WSZ   (CC*CC)    // 262144 = 2^18

typedef short s16x8 __attribute__((ext_vector_type(8)));   // 8 bf16
typedef float f32x4 __attribute__((ext_vector_type(4)));
typedef unsigned short bfu_t;
typedef const __attribute__((address_space(1))) void gv_t;
typedef __attribute__((address_space(3))) void lv_t;

static __device__ __forceinline__ bfu_t f2bu(float f) {
    __bf16 h = (__bf16)f;                       // RNE
    return __builtin_bit_cast(unsigned short, h);
}
static __device__ __forceinline__ float bu2f(unsigned int lo16) {
    unsigned int x = lo16 << 16;
    return __builtin_bit_cast(float, x);
}

// bijective XCD-aware swizzle (m204)
static __device__ __forceinline__ int xcd_swz(int id, int nwg) {
    int q = nwg >> 3, r = nwg & 7;
    int xcd = id & 7, off = id >> 3;
    return (xcd < r ? xcd * (q + 1) : r * (q + 1) + (xcd - r) * q) + off;
}

// ---------------- one-shot fp32 -> bf16 conversion of everything ------------
__global__ __launch_bounds__(256)
void convert_all(const float* __restrict__ Wa, const float* __restrict__ Wb,
                 const float* __restrict__ Wv, const float* __restrict__ Wu,
                 const float* __restrict__ We, const float* __restrict__ x0,
                 const float* __restrict__ e0,
                 bfu_t* __restrict__ WnB, bfu_t* __restrict__ WeB,
                 bfu_t* __restrict__ xbf, bfu_t* __restrict__ ebf)
{
    const long i = (long)(blockIdx.x * 256 + threadIdx.x) * 8;
    const long WTOT = 10L * WSZ;
    const long XTOT = WTOT + (long)XROWS * CC;
    const float* src;
    bfu_t* dst;
    if (i < WTOT) {
        int  c   = (int)(i >> 18);
        long off = i & (WSZ - 1);
        if (c < 8) {
            int l = c >> 2, t = c & 3;
            const float* b = (t == 0) ? Wa : (t == 1) ? Wb : (t == 2) ? Wv : Wu;
            src = b + (long)l * WSZ + off;
            dst = WnB + (long)c * WSZ + off;
        } else {
            src = We + (long)(c - 8) * WSZ + off;
            dst = WeB + (long)(c - 8) * WSZ + off;
        }
    } else if (i < XTOT) {
        long off = i - WTOT;
        src = x0 + off;  dst = xbf + off;
    } else {
        long off = i - XTOT;
        src = e0 + off;  dst = ebf + off;
    }
    float4 a = *(const float4*)src;
    float4 b = *(const float4*)(src + 4);
    s16x8 v;
    v[0] = (short)f2bu(a.x); v[1] = (short)f2bu(a.y);
    v[2] = (short)f2bu(a.z); v[3] = (short)f2bu(a.w);
    v[4] = (short)f2bu(b.x); v[5] = (short)f2bu(b.y);
    v[6] = (short)f2bu(b.z); v[7] = (short)f2bu(b.w);
    *(s16x8*)dst = v;
}

// ---------------- bf16 MFMA GEMM: out = A @ W^T -----------------------------
// mode 0: fp32 out[row*ldo + bn + col] = acc                     (node -> xW)
// mode 1: bf16 outb[row*512 + col] = acc + Ax[i] + Bx[j];
//         per-(colchunk,row) fp32 BN partials {sum,sumsq} -> pstat
__global__ __launch_bounds__(256)
void gemm_mfma(const bfu_t* __restrict__ A, const bfu_t* __restrict__ W,
               float* __restrict__ out, bfu_t* __restrict__ outb,
               int M, int ldo, int gy,
               const float* __restrict__ xW, int mode,
               float2* __restrict__ pstat)
{
    __shared__ bfu_t As[128 * 32];
    __shared__ bfu_t Bs[128 * 32];

    const int nwg  = gridDim.x;
    const int wgid = xcd_swz(blockIdx.x, nwg);
    const int bm   = (wgid / gy) * 128;
    const int by   = wgid % gy;
    const int bn   = by * 128;

    const int t    = threadIdx.x;
    const int lane = t & 63;
    const int w    = t >> 6;
    const int wr   = (w >> 1) * 64;
    const int wc   = (w & 1) * 64;

    f32x4 acc[4][4];
    #pragma unroll
    for (int i = 0; i < 4; ++i)
        #pragma unroll
        for (int j = 0; j < 4; ++j) acc[i][j] = (f32x4){0.f, 0.f, 0.f, 0.f};

    const int r0 = w * 32 + (lane >> 2);
    const int r1 = r0 + 16;
    const int kc = (lane & 3) * 8;
    int ga0 = bm + r0; if (ga0 > M - 1) ga0 = M - 1;
    int ga1 = bm + r1; if (ga1 > M - 1) ga1 = M - 1;
    const bfu_t* a0 = A + (size_t)ga0 * CC + kc;
    const bfu_t* a1 = A + (size_t)ga1 * CC + kc;
    const bfu_t* w0 = W + (size_t)(bn + r0) * CC + kc;
    const bfu_t* w1 = W + (size_t)(bn + r1) * CC + kc;
    bfu_t* lA0 = As + (w * 2 + 0) * 512;
    bfu_t* lA1 = As + (w * 2 + 1) * 512;
    bfu_t* lB0 = Bs + (w * 2 + 0) * 512;
    bfu_t* lB1 = Bs + (w * 2 + 1) * 512;

    const int fra = wr + (lane & 15);
    const int frb = wc + (lane & 15);
    const int fk  = (lane >> 4) * 8;

    for (int kt = 0; kt < CC; kt += 32) {
        if (kt) __syncthreads();
        __builtin_amdgcn_global_load_lds((gv_t*)(a0 + kt), (lv_t*)lA0, 16, 0, 0);
        __builtin_amdgcn_global_load_lds((gv_t*)(a1 + kt), (lv_t*)lA1, 16, 0, 0);
        __builtin_amdgcn_global_load_lds((gv_t*)(w0 + kt), (lv_t*)lB0, 16, 0, 0);
        __builtin_amdgcn_global_load_lds((gv_t*)(w1 + kt), (lv_t*)lB1, 16, 0, 0);
        __syncthreads();

        s16x8 af[4], bfg[4];
        #pragma unroll
        for (int i = 0; i < 4; ++i)
            af[i] = *(const s16x8*)&As[(fra + i * 16) * 32 + fk];
        #pragma unroll
        for (int i = 0; i < 4; ++i)
            bfg[i] = *(const s16x8*)&Bs[(frb + i * 16) * 32 + fk];
        #pragma unroll
        for (int i = 0; i < 4; ++i)
            #pragma unroll
            for (int j = 0; j < 4; ++j)
                acc[i][j] = __builtin_amdgcn_mfma_f32_16x16x32_bf16(af[i], bfg[j], acc[i][j], 0, 0, 0);
    }

    const int crb = wr + ((lane >> 4) << 2);
    const int ccb = wc + (lane & 15);
    if (mode == 0) {
        #pragma unroll
        for (int mi = 0; mi < 4; ++mi) {
            #pragma unroll
            for (int q = 0; q < 4; ++q) {
                int row = bm + crb + mi * 16 + q;
                if (row >= M) continue;
                float* o = out + (size_t)row * ldo + bn + ccb;
                #pragma unroll
                for (int ni = 0; ni < 4; ++ni) o[ni * 16] = acc[mi][ni][q];
            }
        }
    } else {
        const int chunk = by * 2 + (w & 1);      // 8 col-chunks of 64
        #pragma unroll
        for (int mi = 0; mi < 4; ++mi) {
            #pragma unroll
            for (int q = 0; q < 4; ++q) {
                int row = bm + crb + mi * 16 + q;
                if (row >= M) continue;
                int b  = row / NE;
                int e  = row - b * NE;
                int i2 = e / NN;
                int j2 = e - i2 * NN;
                const float* axp = xW + (size_t)(b * NN + i2) * 2048 + bn + ccb;
                const float* bxp = xW + (size_t)(b * NN + j2) * 2048 + 512 + bn + ccb;
                bfu_t* o = outb + (size_t)row * CC + bn + ccb;
                float s = 0.f, sq = 0.f;
                #pragma unroll
                for (int ni = 0; ni < 4; ++ni) {
                    float v = acc[mi][ni][q] + axp[ni * 16] + bxp[ni * 16];
                    o[ni * 16] = f2bu(v);      // m stored bf16
                    s += v; sq += v * v;       // stats from exact fp32
                }
                #pragma unroll
                for (int off = 1; off < 16; off <<= 1) {
                    s  += __shfl_xor(s, off);
                    sq += __shfl_xor(sq, off);
                }
                if ((lane & 15) == 0)
                    pstat[(size_t)chunk * EROWS + row] = make_float2(s, sq);
            }
        }
    }
}

// ---------------- reduce edge BN partials -> kae/kbe; zero node stats -------
__global__ __launch_bounds__(256)
void reduce_estats(const float2* __restrict__ pstat,
                   const float* __restrict__ bnew, const float* __restrict__ bneb,
                   float* __restrict__ kae, float* __restrict__ kbe,
                   float* __restrict__ vstats)
{
    const int e = blockIdx.x;
    const int t = threadIdx.x;
    if (e == 0 && t < 2 * NN) vstats[t] = 0.f;

    float s = 0.f, sq = 0.f;
    #pragma unroll
    for (int k = t; k < 512; k += 256) {
        int chunk = k >> 6, b = k & 63;
        float2 v = pstat[(size_t)chunk * EROWS + (size_t)b * NE + e];
        s += v.x; sq += v.y;
    }
    #pragma unroll
    for (int off = 32; off; off >>= 1) {
        s  += __shfl_down(s, off);
        sq += __shfl_down(sq, off);
    }
    __shared__ float rs[4], rq[4];
    const int wid = t >> 6, lane = t & 63;
    if (lane == 0) { rs[wid] = s; rq[wid] = sq; }
    __syncthreads();
    if (t == 0) {
        s  = rs[0] + rs[1] + rs[2] + rs[3];
        sq = rq[0] + rq[1] + rq[2] + rq[3];
        const float inv = 1.f / (float)(BB * CC);
        float mean = s * inv;
        float var  = sq * inv - mean * mean;
        float r    = rsqrtf(var + EPSV);
        float a    = r * bnew[e];
        kae[e] = a;
        kbe[e] = bneb[e] - mean * a;
    }
}

// ---------------- fused: BN(m)+relu+residual -> eout/ebf -> softmax -> agg --
// block = (b,i) via XCD swizzle; 256 threads x float2. Two-phase: batch all
// 27 m/ein loads into registers first (ILP), then compute.
__global__ __launch_bounds__(256)
void agg_edge(const bfu_t* __restrict__ mbf, const float* __restrict__ ein,
              float* __restrict__ eout, bfu_t* __restrict__ ebf,
              const float* __restrict__ xW, float* __restrict__ xpre,
              const float* __restrict__ kae, const float* __restrict__ kbe,
              float* __restrict__ vsum, float* __restrict__ vsumsq)
{
    const int bi = xcd_swz(blockIdx.x, XROWS);   // 1728 = 8*216, bijective
    const int b  = bi / NN;
    const int i  = bi - b * NN;
    const int c  = threadIdx.x * 2;

    __shared__ float ka_s[NN], kb_s[NN];
    if (threadIdx.x < NN) {
        ka_s[threadIdx.x] = kae[i * NN + threadIdx.x];
        kb_s[threadIdx.x] = kbe[i * NN + threadIdx.x];
    }
    __syncthreads();

    const size_t ebase = ((size_t)b * NE + (size_t)i * NN) * CC + c;

    // phase 1: batch-issue all loads (27 x {u32 m-pair, float2 ein})
    unsigned int mv[NN];
    float2 evv[NN];
    #pragma unroll
    for (int j = 0; j < NN; ++j) {
        size_t idx = ebase + (size_t)j * CC;
        mv[j]  = *(const unsigned int*)(mbf + idx);
        evv[j] = *(const float2*)(ein + idx);
    }

    // phase 2: BN+relu+residual, store eout/ebf, sigmoid->exp
    float2 ex[NN];
    float2 den = {0.f, 0.f};
    #pragma unroll
    for (int j = 0; j < NN; ++j) {
        size_t idx = ebase + (size_t)j * CC;
        float mx = bu2f(mv[j] & 0xffffu);
        float my = bu2f(mv[j] >> 16);
        float a = ka_s[j], bb = kb_s[j];
        float2 o;
        o.x = evv[j].x + fmaxf(fmaf(mx, a, bb), 0.f);
        o.y = evv[j].y + fmaxf(fmaf(my, a, bb), 0.f);
        *(float2*)(eout + idx) = o;
        ushort2 h; h.x = f2bu(o.x); h.y = f2bu(o.y);
        *(ushort2*)(ebf + idx) = h;
        float sx = 1.f / (1.f + __expf(-o.x));
        float sy = 1.f / (1.f + __expf(-o.y));
        float gx = __expf(sx), gy = __expf(sy);
        ex[j].x = gx; ex[j].y = gy;
        den.x += gx; den.y += gy;
    }

    // phase 3: weighted V aggregate + U
    float2 accv = {0.f, 0.f};
    const float* vb = xW + (size_t)(b * NN) * 2048 + 1024 + c;
    #pragma unroll
    for (int j = 0; j < NN; ++j) {
        float2 v = *(const float2*)(vb + (size_t)j * 2048);
        accv.x = fmaf(ex[j].x, v.x, accv.x);
        accv.y = fmaf(ex[j].y, v.y, accv.y);
    }
    float2 u = *(const float2*)(xW + (size_t)bi * 2048 + 1536 + c);
    float2 xp;
    xp.x = u.x + accv.x / (den.x * (float)NN);
    xp.y = u.y + accv.y / (den.y * (float)NN);
    *(float2*)(xpre + (size_t)bi * CC + c) = xp;

    // node-BN partial stats
    float s  = xp.x + xp.y;
    float sq = xp.x * xp.x + xp.y * xp.y;
    #pragma unroll
    for (int off = 32; off; off >>= 1) {
        s  += __shfl_down(s, off);
        sq += __shfl_down(sq, off);
    }
    __shared__ float rs[4], rq[4];
    const int wid = threadIdx.x >> 6, lane = threadIdx.x & 63;
    if (lane == 0) { rs[wid] = s; rq[wid] = sq; }
    __syncthreads();
    if (threadIdx.x == 0) {
        atomicAdd(&vsum[i],   rs[0] + rs[1] + rs[2] + rs[3]);
        atomicAdd(&vsumsq[i], rq[0] + rq[1] + rq[2] + rq[3]);
    }
}

// ---------------- node update: xout = xpre + relu(bn(xpre)), + bf16 copy ----
__global__ __launch_bounds__(256)
void x_update(const float* __restrict__ xpre, float* __restrict__ xout,
              bfu_t* __restrict__ xbf,
              const float* __restrict__ vsum, const float* __restrict__ vsumsq,
              const float* __restrict__ bnvw, const float* __restrict__ bnvb)
{
    const int idx = blockIdx.x * 256 + threadIdx.x;   // float4 idx
    const int i = (idx >> 7) % NN;
    const float inv = 1.f / (float)(BB * CC);
    float mean = vsum[i] * inv;
    float var  = vsumsq[i] * inv - mean * mean;
    float r    = rsqrtf(var + EPSV);
    float a    = r * bnvw[i];
    float b    = bnvb[i] - mean * a;
    float4 v = ((const float4*)xpre)[idx];
    float4 o;
    o.x = v.x + fmaxf(fmaf(v.x, a, b), 0.f);
    o.y = v.y + fmaxf(fmaf(v.y, a, b), 0.f);
    o.z = v.z + fmaxf(fmaf(v.z, a, b), 0.f);
    o.w = v.w + fmaxf(fmaf(v.w, a, b), 0.f);
    ((float4*)xout)[idx] = o;
    ushort4 h;
    h.x = f2bu(o.x); h.y = f2bu(o.y); h.z = f2bu(o.z); h.w = f2bu(o.w);
    ((ushort4*)xbf)[idx] = h;
}

// ---------------------------------------------------------------------------
extern "C" void kernel_launch(void* const* d_in, const int* in_sizes, int n_in,
                              void* d_out, int out_size, void* d_ws, size_t ws_size,
                              hipStream_t stream)
{
    const float* x0   = (const float*)d_in[0];
    const float* e0   = (const float*)d_in[1];
    const float* Wu   = (const float*)d_in[2];
    const float* Wv   = (const float*)d_in[3];
    const float* Wa   = (const float*)d_in[4];
    const float* Wb   = (const float*)d_in[5];
    const float* We   = (const float*)d_in[6];
    const float* bnvw = (const float*)d_in[7];
    const float* bnvb = (const float*)d_in[8];
    const float* bnew = (const float*)d_in[9];
    const float* bneb = (const float*)d_in[10];

    const size_t XSZ = (size_t)XROWS * CC;     // 884736
    const size_t ESZ = (size_t)EROWS * CC;     // 23887872

    float* xout = (float*)d_out;
    float* eout = xout + XSZ;

    // fp32 workspace
    float* ws    = (float*)d_ws;
    float* xW    = ws;                          // [1728][2048] A|B|V|U cols
    float* xpre  = xW + (size_t)XROWS * 2048;
    float* kae   = xpre + XSZ;                  // 729
    float* kbe   = kae + NE;                    // 729
    float* vstats = kbe + NE;                   // 54 (+pad to 64)
    float* vsum   = vstats;
    float* vsumsq = vstats + NN;
    float2* pstat = (float2*)(vstats + 64);     // [8][EROWS] float2
    // bf16 workspace
    bfu_t* bws = (bfu_t*)(pstat + (size_t)8 * EROWS);
    bfu_t* mb  = bws;                                  // m, bf16 [46656][512]
    bfu_t* ebf = mb + ESZ;                             // [46656][512]
    bfu_t* xbf = ebf + ESZ;                            // [1728][512]
    bfu_t* WnB = xbf + XSZ;                            // [L][2048][512]
    bfu_t* WeB = WnB + (size_t)2 * 2048 * CC;          // [L][512][512]

    const long CTOT = 10L * WSZ + (long)XSZ + (long)ESZ;
    convert_all<<<(int)(CTOT / 8 / 256), 256, 0, stream>>>(
        Wa, Wb, Wv, Wu, We, x0, e0, WnB, WeB, xbf, ebf);

    const int nwgN = 14 * 16;     // node: M=1728 (14), N=2048 (16)
    const int nwgE = 365 * 4;     // edge: M=46656 (365), N=512 (4)

    for (int l = 0; l < 2; ++l) {
        const float* ei = l ? (const float*)eout : e0;

        gemm_mfma<<<nwgN, 256, 0, stream>>>(xbf, WnB + (size_t)l * 4 * WSZ,
                                            xW, nullptr, XROWS, 2048, 16,
                                            nullptr, 0, nullptr);
        gemm_mfma<<<nwgE, 256, 0, stream>>>(ebf, WeB + (size_t)l * WSZ,
                                            nullptr, mb, EROWS, CC, 4,
                                            xW, 1, pstat);

        reduce_estats<<<NE, 256, 0, stream>>>(pstat,
                                              bnew + (size_t)l * NE,
                                              bneb + (size_t)l * NE,
                                              kae, kbe, vstats);

        agg_edge<<<XROWS, 256, 0, stream>>>(mb, ei, eout, ebf, xW, xpre,
                                            kae, kbe, vsum, vsumsq);

        x_update<<<(int)(XSZ / 4 / 256), 256, 0, stream>>>(
            xpre, xout, xbf, vsum, vsumsq,
            bnvw + (size_t)l * NN, bnvb + (size_t)l * NN);
    }
}